// Round 8
// baseline (1797.474 us; speedup 1.0000x reference)
//
#include <hip/hip_runtime.h>
#include <hip/hip_bf16.h>

#define TSTEPS 2048
#define NB 64
#define DH 256
#define NBDH (NB * DH)

typedef __attribute__((ext_vector_type(8))) short short8;
typedef __attribute__((ext_vector_type(4))) float f32x4;

__device__ __forceinline__ unsigned short f2bf(float f) {
  union { float f; unsigned u; } v; v.f = f;
  unsigned u = v.u;
  u += 0x7FFFu + ((u >> 16) & 1u);   // round-to-nearest-even
  return (unsigned short)(u >> 16);
}

__device__ __forceinline__ float fast_tanh(float x) {
  // tanh(x) = 1 - 2/(e^{2x}+1); saturates correctly at +/-1
  float e = __builtin_amdgcn_exp2f(x * 2.885390081777927f);  // e^{2x}
  return 1.0f - 2.0f * __builtin_amdgcn_rcpf(e + 1.0f);
}

// hidden-index permutation (self-inverse nibble swap): klin <-> c
__device__ __forceinline__ int T16(int p) { return ((p & 15) << 4) | (p >> 4); }

// ---- kernel 0: f32 -> bf16 weights; W_hid / W_out k-dim stored in klin order
__global__ void cvt_w(const float* __restrict__ a, const float* __restrict__ b,
                      const float* __restrict__ c, unsigned short* __restrict__ dst) {
  int i = blockIdx.x * 256 + threadIdx.x;  // 0 .. 3*65536-1
  int mat = i >> 16, idx = i & 65535;
  float s;
  if (mat == 0) {
    s = a[idx];                                        // W_in: unpermuted
  } else {
    int n = idx >> 8, klin = idx & 255;
    s = (mat == 1 ? b : c)[n * 256 + T16(klin)];
  }
  dst[i] = f2bf(s);
}

// ---- kernel 1: input GEMM, one block per (t, bb): C[16 rows][256] = x @ W_in^T,
// output stored in the scan's exact fragment layout:
// xps[ seg=(((t*4+bb)*4+w)*4+nt) ][ lane ][ r(f32x4) ]  -- 16B/lane stores.
__global__ __launch_bounds__(256) void gemm_in(
    const float* __restrict__ x, const unsigned short* __restrict__ Wbf,
    float* __restrict__ xps) {
  const int w = threadIdx.x >> 6, l = threadIdx.x & 63;
  const int m16 = l & 15, kg = l >> 4;
  const int t = blockIdx.x >> 2, bb = blockIdx.x & 3;

  short8 a[8];
  {
    const float* xr = x + ((long)t * NB + bb * 16 + m16) * 256 + kg * 8;
    for (int ks = 0; ks < 8; ++ks) {
      float4 f0 = *(const float4*)(xr + ks * 32);
      float4 f1 = *(const float4*)(xr + ks * 32 + 4);
      unsigned p0, p1, p2, p3;
      asm("v_cvt_pk_bf16_f32 %0, %1, %2" : "=v"(p0) : "v"(f0.x), "v"(f0.y));
      asm("v_cvt_pk_bf16_f32 %0, %1, %2" : "=v"(p1) : "v"(f0.z), "v"(f0.w));
      asm("v_cvt_pk_bf16_f32 %0, %1, %2" : "=v"(p2) : "v"(f1.x), "v"(f1.y));
      asm("v_cvt_pk_bf16_f32 %0, %1, %2" : "=v"(p3) : "v"(f1.z), "v"(f1.w));
      union { unsigned u[4]; short8 s; } uu;
      uu.u[0] = p0; uu.u[1] = p1; uu.u[2] = p2; uu.u[3] = p3;
      a[ks] = uu.s;
    }
  }
  short8 bf[4][8];
  for (int nt = 0; nt < 4; ++nt) {
    const unsigned short* wr = Wbf + (w * 64 + nt * 16 + m16) * 256 + kg * 8;
    for (int ks = 0; ks < 8; ++ks) bf[nt][ks] = *(const short8*)(wr + ks * 32);
  }
  f32x4 acc[4] = {{0,0,0,0},{0,0,0,0},{0,0,0,0},{0,0,0,0}};
  for (int ks = 0; ks < 8; ++ks)
    for (int nt = 0; nt < 4; ++nt)
      acc[nt] = __builtin_amdgcn_mfma_f32_16x16x32_bf16(a[ks], bf[nt][ks], acc[nt], 0, 0, 0);
  for (int nt = 0; nt < 4; ++nt)
    *(f32x4*)(xps + ((((long)t * 4 + bb) * 4 + w) * 4 + nt) * 256 + l * 4) = acc[nt];
}

// ---- kernel 2: sequential scan. 4 blocks x 16 batch rows, 4 waves x 64 cols.
// h in LDS [16 rows][264] bf16 (row stride 528B), klin col order.
// Per step per CU: 32 ds_read_b128 + 16 ds_write_b64 (~480cy) < 128 MFMA (~620cy).
__global__ __launch_bounds__(256, 1) void rnn_scan(
    const float* __restrict__ xps, const unsigned short* __restrict__ Wbf,
    const float* __restrict__ h0, unsigned short* __restrict__ hsp) {
  __shared__ unsigned short h[2 * 16 * 264];
  const int tid = threadIdx.x, w = tid >> 6, l = tid & 63;
  const int m16 = l & 15, kg = l >> 4;
  const int bb = blockIdx.x;

  short8 bf[4][8];                       // W_hid fragments: 128 VGPR, resident
  for (int nt = 0; nt < 4; ++nt) {
    const unsigned short* wr = Wbf + (w * 64 + nt * 16 + m16) * 256 + kg * 8;
    for (int ks = 0; ks < 8; ++ks) bf[nt][ks] = *(const short8*)(wr + ks * 32);
  }

  {                                      // h0 ingest (klin order)
    int row = tid >> 4, q = tid & 15;
    for (int j = 0; j < 16; ++j)
      h[row * 264 + q * 16 + j] = f2bf(h0[(bb * 16 + row) * 256 + ((j << 4) | q)]);
  }
  __syncthreads();

  const unsigned short* rda = h + m16 * 264 + kg * 8;
  const f32x4* xpv = (const f32x4*)xps;

#define XPLD(T, NT) xpv[((((long)(T) * 4 + bb) * 4 + w) * 4 + (NT)) * 64 + l]
  f32x4 xA0 = XPLD(0, 0), xA1 = XPLD(0, 1), xA2 = XPLD(0, 2), xA3 = XPLD(0, 3);
  f32x4 xB0 = XPLD(1, 0), xB1 = XPLD(1, 1), xB2 = XPLD(1, 2), xB3 = XPLD(1, 3);

#define M16X(A, B, C) __builtin_amdgcn_mfma_f32_16x16x32_bf16(A, B, C, 0, 0, 0)
#define RNN_STEP(T, CUR, X0, X1, X2, X3, PF)                                        \
  {                                                                                 \
    const short8* ap = (const short8*)(rda + (CUR) * 4224);                         \
    short8 a0 = ap[0],  a1 = ap[4],  a2 = ap[8],  a3 = ap[12];                      \
    short8 a4 = ap[16], a5 = ap[20], a6 = ap[24], a7 = ap[28];                      \
    f32x4 c0a = X0, c1a = X1, c2a = X2, c3a = X3;                                   \
    f32x4 c0b = {0,0,0,0}, c1b = {0,0,0,0}, c2b = {0,0,0,0}, c3b = {0,0,0,0};       \
    if (PF) {                                                                       \
      X0 = XPLD((T) + 2, 0); X1 = XPLD((T) + 2, 1);                                 \
      X2 = XPLD((T) + 2, 2); X3 = XPLD((T) + 2, 3);                                 \
    }                                                                               \
    c0a = M16X(a0, bf[0][0], c0a); c1a = M16X(a0, bf[1][0], c1a);                   \
    c2a = M16X(a0, bf[2][0], c2a); c3a = M16X(a0, bf[3][0], c3a);                   \
    c0b = M16X(a4, bf[0][4], c0b); c1b = M16X(a4, bf[1][4], c1b);                   \
    c2b = M16X(a4, bf[2][4], c2b); c3b = M16X(a4, bf[3][4], c3b);                   \
    c0a = M16X(a1, bf[0][1], c0a); c1a = M16X(a1, bf[1][1], c1a);                   \
    c2a = M16X(a1, bf[2][1], c2a); c3a = M16X(a1, bf[3][1], c3a);                   \
    c0b = M16X(a5, bf[0][5], c0b); c1b = M16X(a5, bf[1][5], c1b);                   \
    c2b = M16X(a5, bf[2][5], c2b); c3b = M16X(a5, bf[3][5], c3b);                   \
    c0a = M16X(a2, bf[0][2], c0a); c1a = M16X(a2, bf[1][2], c1a);                   \
    c2a = M16X(a2, bf[2][2], c2a); c3a = M16X(a2, bf[3][2], c3a);                   \
    c0b = M16X(a6, bf[0][6], c0b); c1b = M16X(a6, bf[1][6], c1b);                   \
    c2b = M16X(a6, bf[2][6], c2b); c3b = M16X(a6, bf[3][6], c3b);                   \
    c0a = M16X(a3, bf[0][3], c0a); c1a = M16X(a3, bf[1][3], c1a);                   \
    c2a = M16X(a3, bf[2][3], c2a); c3a = M16X(a3, bf[3][3], c3a);                   \
    c0b = M16X(a7, bf[0][7], c0b); c1b = M16X(a7, bf[1][7], c1b);                   \
    c2b = M16X(a7, bf[2][7], c2b); c3b = M16X(a7, bf[3][7], c3b);                   \
    for (int r = 0; r < 4; ++r) {                                                   \
      float v0 = fast_tanh(c0a[r] + c0b[r]);                                        \
      float v1 = fast_tanh(c1a[r] + c1b[r]);                                        \
      float v2 = fast_tanh(c2a[r] + c2b[r]);                                        \
      float v3 = fast_tanh(c3a[r] + c3b[r]);                                        \
      unsigned pk0, pk1;                                                            \
      asm("v_cvt_pk_bf16_f32 %0, %1, %2" : "=v"(pk0) : "v"(v0), "v"(v1));           \
      asm("v_cvt_pk_bf16_f32 %0, %1, %2" : "=v"(pk1) : "v"(v2), "v"(v3));           \
      uint2 u; u.x = pk0; u.y = pk1;                                                \
      *(uint2*)(h + (((CUR) ^ 1) * 4224) + (kg * 4 + r) * 264 + m16 * 16 + w * 4) = u; \
      *(uint2*)(hsp + ((long)(T) * 64 + bb * 16 + kg * 4 + r) * 256 + m16 * 16 + w * 4) = u; \
    }                                                                               \
    asm volatile("s_waitcnt lgkmcnt(0)" ::: "memory"); /* LDS drain only */         \
    __builtin_amdgcn_s_barrier();                                                   \
    __builtin_amdgcn_sched_barrier(0);                                              \
  }

#pragma unroll 1
  for (int t = 0; t < TSTEPS - 2; t += 2) {
    RNN_STEP(t, 0, xA0, xA1, xA2, xA3, true);
    RNN_STEP(t + 1, 1, xB0, xB1, xB2, xB3, true);
  }
  RNN_STEP(TSTEPS - 2, 0, xA0, xA1, xA2, xA3, false);
  RNN_STEP(TSTEPS - 1, 1, xB0, xB1, xB2, xB3, false);
#undef RNN_STEP
#undef M16X
#undef XPLD
}

// ---- kernel 3: output GEMM, ys[M,256] = hs_p[M,klin] * Wout_p[n,klin]^T
__global__ __launch_bounds__(256) void gemm_out(
    const unsigned short* __restrict__ Abf, const unsigned short* __restrict__ Wbf,
    float* __restrict__ Cout) {
  const int w = threadIdx.x >> 6, l = threadIdx.x & 63;
  const int m16 = l & 15, kg = l >> 4;
  const long tile0 = ((long)blockIdx.x * 4 + w) * 2;

  short8 afr[2][8];
  for (int ti = 0; ti < 2; ++ti) {
    const unsigned short* ar = Abf + ((tile0 + ti) * 16 + m16) * 256 + kg * 8;
    for (int ks = 0; ks < 8; ++ks) afr[ti][ks] = *(const short8*)(ar + ks * 32);
  }
  for (int nt = 0; nt < 16; ++nt) {
    const int n = nt * 16 + m16;
    const unsigned short* wr = Wbf + n * 256 + kg * 8;
    f32x4 acc0 = {0.f, 0.f, 0.f, 0.f}, acc1 = {0.f, 0.f, 0.f, 0.f};
    for (int ks = 0; ks < 8; ++ks) {
      short8 b = *(const short8*)(wr + ks * 32);
      acc0 = __builtin_amdgcn_mfma_f32_16x16x32_bf16(afr[0][ks], b, acc0, 0, 0, 0);
      acc1 = __builtin_amdgcn_mfma_f32_16x16x32_bf16(afr[1][ks], b, acc1, 0, 0, 0);
    }
    for (int r = 0; r < 4; ++r) {
      Cout[(tile0 * 16 + kg * 4 + r) * 256 + n]       = acc0[r];
      Cout[((tile0 + 1) * 16 + kg * 4 + r) * 256 + n] = acc1[r];
    }
  }
}

// ---- kernel 4: h_last[b][c] = f32(hs_p[T-1][b][klin]), un-permuting cols
__global__ void hlast_k(const unsigned short* __restrict__ hs, float* __restrict__ hlast) {
  int i = blockIdx.x * 1024 + threadIdx.x;          // 16 blocks x 1024 = 16384
  int b = i >> 8, klin = i & 255;
  unsigned u = (unsigned)hs[(long)(TSTEPS - 1) * NBDH + i] << 16;
  union { unsigned u; float f; } v; v.u = u;
  hlast[b * 256 + T16(klin)] = v.f;
}

extern "C" void kernel_launch(void* const* d_in, const int* in_sizes, int n_in,
                              void* d_out, int out_size, void* d_ws, size_t ws_size,
                              hipStream_t stream) {
  const float* x    = (const float*)d_in[0];
  const float* h0   = (const float*)d_in[1];
  const float* Win  = (const float*)d_in[2];
  const float* Whid = (const float*)d_in[3];
  const float* Wout = (const float*)d_in[4];
  float* ys    = (float*)d_out;
  float* hlast = ys + (long)TSTEPS * NB * 256;

  // d_ws: [bf16 W_in | bf16 Whid_p | bf16 Wout_p | f32 xp frag-layout (128MB) | bf16 hs_p (64MB)]
  unsigned short* wbf     = (unsigned short*)d_ws;
  unsigned short* wbf_in  = wbf;
  unsigned short* wbf_hid = wbf + 65536;
  unsigned short* wbf_out = wbf + 131072;
  float* xproj = (float*)((char*)d_ws + 393216);
  unsigned short* hsbuf =
      (unsigned short*)((char*)d_ws + 393216 + (size_t)TSTEPS * NB * 256 * 4);

  cvt_w<<<dim3(768), dim3(256), 0, stream>>>(Win, Whid, Wout, wbf);
  gemm_in<<<dim3(TSTEPS * 4), dim3(256), 0, stream>>>(x, wbf_in, xproj);
  rnn_scan<<<dim3(4), dim3(256), 0, stream>>>(xproj, wbf_hid, h0, hsbuf);
  gemm_out<<<dim3(1024), dim3(256), 0, stream>>>(hsbuf, wbf_out, ys);
  hlast_k<<<dim3(16), dim3(1024), 0, stream>>>(hsbuf, hlast);
}

// Round 10
// 886.944 us; speedup vs baseline: 2.0266x; 2.0266x over previous
//
#include <hip/hip_runtime.h>
#include <hip/hip_bf16.h>

#define TSTEPS 2048
#define NB 64
#define DH 256
#define NBDH (NB * DH)

typedef __attribute__((ext_vector_type(8))) short short8;
typedef __attribute__((ext_vector_type(4))) float f32x4;
typedef __attribute__((ext_vector_type(4))) int i32x4;

#define WSCALE 2032.0f
#define HSCALE 127.0f
#define INVSC (1.0f / (2032.0f * 127.0f))

__device__ __forceinline__ unsigned short f2bf(float f) {
  union { float f; unsigned u; } v; v.f = f;
  unsigned u = v.u;
  u += 0x7FFFu + ((u >> 16) & 1u);   // round-to-nearest-even
  return (unsigned short)(u >> 16);
}

__device__ __forceinline__ float fast_tanh(float x) {
  // tanh(x) = 1 - 2/(e^{2x}+1); saturates correctly at +/-1
  float e = __builtin_amdgcn_exp2f(x * 2.885390081777927f);  // e^{2x}
  return 1.0f - 2.0f * __builtin_amdgcn_rcpf(e + 1.0f);
}

// klin pairing permutation (r3-verified): LDS/hs pos p <-> orig col c
// p = g*32 + 2*j + half  <->  c = g*32 + half*16 + j
__device__ __forceinline__ int p2c(int p) {
  int q = p & 31;
  return (p & ~31) | ((q & 1) << 4) | (q >> 1);
}

// ---- kernel 0: weights. W_in -> bf16 (unpermuted); W_out -> bf16 k-permuted
// (klin); W_hid -> int8 k-permuted (klin), scale 2032.
__global__ void cvt_w(const float* __restrict__ win, const float* __restrict__ whid,
                      const float* __restrict__ wout, unsigned short* __restrict__ wbf,
                      char* __restrict__ wq) {
  int i = blockIdx.x * 256 + threadIdx.x;  // 0 .. 3*65536-1
  int mat = i >> 16, idx = i & 65535;
  int n = idx >> 8, klin = idx & 255;
  if (mat == 0) {
    wbf[idx] = f2bf(win[idx]);
  } else if (mat == 1) {
    wbf[65536 + idx] = f2bf(wout[n * 256 + p2c(klin)]);
  } else {
    float v = whid[n * 256 + p2c(klin)] * WSCALE;
    int q = (int)__builtin_rintf(fminf(fmaxf(v, -127.f), 127.f));
    wq[idx] = (char)q;
  }
}

// ---- kernel 1: input GEMM  xp[M,256] = x[M,256] @ W_in^T  (f32 out, r2-proven)
__global__ __launch_bounds__(256) void gemm_in(
    const float* __restrict__ x, const unsigned short* __restrict__ Wbf,
    float* __restrict__ Cout) {
  const int w = threadIdx.x >> 6, l = threadIdx.x & 63;
  const int m16 = l & 15, kg = l >> 4;
  const long tile0 = ((long)blockIdx.x * 4 + w) * 2;

  short8 afr[2][8];
  for (int ti = 0; ti < 2; ++ti) {
    const float* ar = x + ((tile0 + ti) * 16 + m16) * 256 + kg * 8;
    for (int ks = 0; ks < 8; ++ks) {
      float4 f0 = *(const float4*)(ar + ks * 32);
      float4 f1 = *(const float4*)(ar + ks * 32 + 4);
      short8 s;
      s[0] = (short)f2bf(f0.x); s[1] = (short)f2bf(f0.y);
      s[2] = (short)f2bf(f0.z); s[3] = (short)f2bf(f0.w);
      s[4] = (short)f2bf(f1.x); s[5] = (short)f2bf(f1.y);
      s[6] = (short)f2bf(f1.z); s[7] = (short)f2bf(f1.w);
      afr[ti][ks] = s;
    }
  }
  for (int nt = 0; nt < 16; ++nt) {
    const int n = nt * 16 + m16;
    const unsigned short* wr = Wbf + n * 256 + kg * 8;
    f32x4 acc0 = {0.f, 0.f, 0.f, 0.f}, acc1 = {0.f, 0.f, 0.f, 0.f};
    for (int ks = 0; ks < 8; ++ks) {
      short8 b = *(const short8*)(wr + ks * 32);
      acc0 = __builtin_amdgcn_mfma_f32_16x16x32_bf16(afr[0][ks], b, acc0, 0, 0, 0);
      acc1 = __builtin_amdgcn_mfma_f32_16x16x32_bf16(afr[1][ks], b, acc1, 0, 0, 0);
    }
    for (int r = 0; r < 4; ++r) {
      Cout[(tile0 * 16 + kg * 4 + r) * 256 + n]       = acc0[r];
      Cout[((tile0 + 1) * 16 + kg * 4 + r) * 256 + n] = acc1[r];
    }
  }
}

// ---- kernel 2: sequential scan, INT8 recurrence. 64 blocks x 1 batch row,
// 8 waves x 32 cols (r2 skeleton). h in LDS as 256 int8 in klin order,
// double-buffered. A-reads: 4 ds_read_b128, kg-broadcast.
// NOTE: xp value for step T is captured into xq0/xq1 BEFORE the t+4 prefetch
// overwrites XV (this was r8's bug).
__global__ __launch_bounds__(512, 2) void rnn_scan(
    const float* __restrict__ xp, const char* __restrict__ Wq,
    const float* __restrict__ h0, unsigned short* __restrict__ hs) {
  __shared__ __align__(16) char hq[2][256];
  const int tid = threadIdx.x, w = tid >> 6, l = tid & 63;
  const int b = blockIdx.x;           // one batch row per block
  const int m16 = l & 15, kg = l >> 4;

  // W_hid i8 B-fragments resident: wave owns orig cols [w*32, w*32+32)
  i32x4 bq[2][4];
  for (int nt = 0; nt < 2; ++nt) {
    const char* wr = Wq + (w * 32 + nt * 16 + m16) * 256 + kg * 16;
    for (int ks = 0; ks < 4; ++ks) bq[nt][ks] = *(const i32x4*)(wr + ks * 64);
  }

  if (tid < 256) {                    // h0 ingest (klin order), quantized
    float v = fminf(fmaxf(h0[b * 256 + p2c(tid)], -1.f), 1.f) * HSCALE;
    hq[0][tid] = (char)(int)__builtin_rintf(v);
  }
  __syncthreads();

  const int col0 = w * 32 + m16;                        // orig col of output t0
  const char* rda = &hq[0][0] + kg * 16;                // + CUR*256 + ks*64 (imm)
  const float* xpb = xp + (long)b * 256 + col0;         // + t*NBDH
  unsigned* hsw = (unsigned*)(hs + (long)b * 256 + w * 32 + 2 * m16);  // + t*8192

  // 4-deep xp prefetch rotation (loads only on data-carrying lanes)
  float xv0[2], xv1[2], xv2[2], xv3[2];
  if (l < 16) {
    xv0[0] = xpb[0];               xv0[1] = xpb[16];
    xv1[0] = xpb[1L * NBDH];       xv1[1] = xpb[1L * NBDH + 16];
    xv2[0] = xpb[2L * NBDH];       xv2[1] = xpb[2L * NBDH + 16];
    xv3[0] = xpb[3L * NBDH];       xv3[1] = xpb[3L * NBDH + 16];
  }

#define MI8(A, B, C) __builtin_amdgcn_mfma_i32_16x16x64_i8(A, B, C, 0, 0, 0)
#define RNN_STEP(T, CUR, XV, PF)                                              \
  {                                                                           \
    const char* ap = rda + (CUR) * 256;                                       \
    i32x4 a0 = *(const i32x4*)(ap);                                           \
    i32x4 a1 = *(const i32x4*)(ap + 64);                                      \
    i32x4 a2 = *(const i32x4*)(ap + 128);                                     \
    i32x4 a3 = *(const i32x4*)(ap + 192);                                     \
    float xq0 = XV[0], xq1 = XV[1];   /* capture THIS step's xp first */      \
    i32x4 c0 = {0, 0, 0, 0}, c1 = {0, 0, 0, 0};                               \
    if ((PF) && l < 16) {             /* now safe to prefetch t+4 */          \
      const float* q = xpb + (long)((T) + 4) * NBDH;                          \
      XV[0] = q[0]; XV[1] = q[16];                                            \
    }                                                                         \
    c0 = MI8(a0, bq[0][0], c0); c1 = MI8(a0, bq[1][0], c1);                   \
    c0 = MI8(a1, bq[0][1], c0); c1 = MI8(a1, bq[1][1], c1);                   \
    c0 = MI8(a2, bq[0][2], c0); c1 = MI8(a2, bq[1][2], c1);                   \
    c0 = MI8(a3, bq[0][3], c0); c1 = MI8(a3, bq[1][3], c1);                   \
    float z0 = (float)c0[0] * INVSC + xq0;                                    \
    float z1 = (float)c1[0] * INVSC + xq1;                                    \
    float t0 = fast_tanh(z0), t1 = fast_tanh(z1);                             \
    unsigned pk;                                                              \
    asm("v_cvt_pk_bf16_f32 %0, %1, %2" : "=v"(pk) : "v"(t0), "v"(t1));        \
    int q0 = (int)__builtin_rintf(t0 * HSCALE);                               \
    int q1 = (int)__builtin_rintf(t1 * HSCALE);                               \
    unsigned short uq = (unsigned short)((q0 & 0xFF) | ((q1 & 0xFF) << 8));   \
    if (l < 16) {                                                             \
      *(unsigned short*)(&hq[(CUR) ^ 1][w * 32 + 2 * l]) = uq;                \
      hsw[(long)(T) * 8192] = pk;                                             \
    }                                                                         \
    asm volatile("s_waitcnt lgkmcnt(0)" ::: "memory");  /* LDS drain only */  \
    __builtin_amdgcn_s_barrier();                                             \
    __builtin_amdgcn_sched_barrier(0);                                        \
  }

#pragma unroll 1
  for (int t = 0; t < TSTEPS - 4; t += 4) {
    RNN_STEP(t, 0, xv0, true);
    RNN_STEP(t + 1, 1, xv1, true);
    RNN_STEP(t + 2, 0, xv2, true);
    RNN_STEP(t + 3, 1, xv3, true);
  }
  RNN_STEP(TSTEPS - 4, 0, xv0, false);
  RNN_STEP(TSTEPS - 3, 1, xv1, false);
  RNN_STEP(TSTEPS - 2, 0, xv2, false);
  RNN_STEP(TSTEPS - 1, 1, xv3, false);
#undef RNN_STEP
#undef MI8
}

// ---- kernel 3: output GEMM, ys[M,256] = hs[M,klin] @ Wout_p[n,klin]^T (bf16 A)
__global__ __launch_bounds__(256) void gemm_out(
    const unsigned short* __restrict__ Abf, const unsigned short* __restrict__ Wbf,
    float* __restrict__ Cout) {
  const int w = threadIdx.x >> 6, l = threadIdx.x & 63;
  const int m16 = l & 15, kg = l >> 4;
  const long tile0 = ((long)blockIdx.x * 4 + w) * 2;

  short8 afr[2][8];
  for (int ti = 0; ti < 2; ++ti) {
    const unsigned short* ar = Abf + ((tile0 + ti) * 16 + m16) * 256 + kg * 8;
    for (int ks = 0; ks < 8; ++ks) afr[ti][ks] = *(const short8*)(ar + ks * 32);
  }
  for (int nt = 0; nt < 16; ++nt) {
    const int n = nt * 16 + m16;
    const unsigned short* wr = Wbf + n * 256 + kg * 8;
    f32x4 acc0 = {0.f, 0.f, 0.f, 0.f}, acc1 = {0.f, 0.f, 0.f, 0.f};
    for (int ks = 0; ks < 8; ++ks) {
      short8 b = *(const short8*)(wr + ks * 32);
      acc0 = __builtin_amdgcn_mfma_f32_16x16x32_bf16(afr[0][ks], b, acc0, 0, 0, 0);
      acc1 = __builtin_amdgcn_mfma_f32_16x16x32_bf16(afr[1][ks], b, acc1, 0, 0, 0);
    }
    for (int r = 0; r < 4; ++r) {
      Cout[(tile0 * 16 + kg * 4 + r) * 256 + n]       = acc0[r];
      Cout[((tile0 + 1) * 16 + kg * 4 + r) * 256 + n] = acc1[r];
    }
  }
}

// ---- kernel 4: h_last[b][c] = f32(hs[T-1][b][klin]), un-permuting columns
__global__ void hlast_k(const unsigned short* __restrict__ hs, float* __restrict__ hlast) {
  int i = blockIdx.x * 1024 + threadIdx.x;          // 16 blocks x 1024 = 16384
  int b = i >> 8, p = i & 255;
  unsigned u = (unsigned)hs[(long)(TSTEPS - 1) * NBDH + b * 256 + p] << 16;
  union { unsigned u; float f; } v; v.u = u;
  hlast[b * 256 + p2c(p)] = v.f;
}

extern "C" void kernel_launch(void* const* d_in, const int* in_sizes, int n_in,
                              void* d_out, int out_size, void* d_ws, size_t ws_size,
                              hipStream_t stream) {
  const float* x    = (const float*)d_in[0];
  const float* h0   = (const float*)d_in[1];
  const float* Win  = (const float*)d_in[2];
  const float* Whid = (const float*)d_in[3];
  const float* Wout = (const float*)d_in[4];
  float* ys    = (float*)d_out;
  float* hlast = ys + (long)TSTEPS * NB * 256;

  // d_ws: [bf16 W_in | bf16 Wout_p | i8 Whid_q | f32 xp (128MB) | bf16 hs klin (64MB)]
  unsigned short* wbf     = (unsigned short*)d_ws;               // 2x65536 u16
  unsigned short* wbf_in  = wbf;
  unsigned short* wbf_out = wbf + 65536;
  char* wq_hid = (char*)d_ws + 262144;                           // 65536 B
  float* xproj = (float*)((char*)d_ws + 393216);
  unsigned short* hsbuf =
      (unsigned short*)((char*)d_ws + 393216 + (size_t)TSTEPS * NB * 256 * 4);

  cvt_w<<<dim3(768), dim3(256), 0, stream>>>(Win, Whid, Wout, wbf, wq_hid);
  gemm_in<<<dim3(1024), dim3(256), 0, stream>>>(x, wbf_in, xproj);
  rnn_scan<<<dim3(64), dim3(512), 0, stream>>>(xproj, wq_hid, h0, hsbuf);
  gemm_out<<<dim3(1024), dim3(256), 0, stream>>>(hsbuf, wbf_out, ys);
  hlast_k<<<dim3(16), dim3(1024), 0, stream>>>(hsbuf, hlast);
}